// Round 1
// baseline (580.114 us; speedup 1.0000x reference)
//
#include <hip/hip_runtime.h>

#define NCOL 110592          // 48*48*48
#define NCH  64              // channels C
#define CN   (NCOL * NCH)    // 7077888 elements per batch
#define NB   8

typedef __attribute__((ext_vector_type(8))) __bf16 bf16x8;
typedef __attribute__((ext_vector_type(4))) float  f32x4;

// ---------------------------------------------------------------------------
// K1: partial Gram G_partial = K_chunk * K_chunk^T via bf16 MFMA.
// A-frag and B-frag of a Gram share the same per-lane layout
// (row = lane&15, k = quad*8+j), so fragments load DIRECTLY from global.
// Block = 256 threads = 4 waves; wave w owns output row-tile w (16 rows),
// computes 4 column-tiles -> full 64x64 partial per block, no LDS.
// chunks=128 -> 1024 blocks -> 4 blocks/CU (was 2) for latency hiding.
// ---------------------------------------------------------------------------
__global__ __launch_bounds__(256) void k_gram(const float* __restrict__ x,
                                              float* __restrict__ part,
                                              int steps) {
    const int b     = blockIdx.y;
    const int chunk = blockIdx.x;
    const int tid   = threadIdx.x;
    const int w     = tid >> 6;          // wave id 0..3 -> row-tile
    const int lane  = tid & 63;
    const int r     = lane & 15;
    const int q     = lane >> 4;

    const float* xb = x + (size_t)b * CN;

    f32x4 acc0 = {0.f, 0.f, 0.f, 0.f};
    f32x4 acc1 = {0.f, 0.f, 0.f, 0.f};
    f32x4 acc2 = {0.f, 0.f, 0.f, 0.f};
    f32x4 acc3 = {0.f, 0.f, 0.f, 0.f};

    const int kbase = chunk * steps * 32 + q * 8;

    for (int s = 0; s < steps; ++s) {
        const int k0 = kbase + s * 32;
        bf16x8 frag[4];
#pragma unroll
        for (int i = 0; i < 4; ++i) {
            const float* p = xb + (size_t)(i * 16 + r) * NCOL + k0;
            f32x4 lo = *(const f32x4*)p;
            f32x4 hi = *(const f32x4*)(p + 4);
            bf16x8 f;
            f[0] = (__bf16)lo[0]; f[1] = (__bf16)lo[1];
            f[2] = (__bf16)lo[2]; f[3] = (__bf16)lo[3];
            f[4] = (__bf16)hi[0]; f[5] = (__bf16)hi[1];
            f[6] = (__bf16)hi[2]; f[7] = (__bf16)hi[3];
            frag[i] = f;
        }
        // select this wave's A-fragment (avoid dynamic register indexing)
        bf16x8 af = (w == 0) ? frag[0] : (w == 1) ? frag[1]
                  : (w == 2) ? frag[2] : frag[3];
        acc0 = __builtin_amdgcn_mfma_f32_16x16x32_bf16(af, frag[0], acc0, 0, 0, 0);
        acc1 = __builtin_amdgcn_mfma_f32_16x16x32_bf16(af, frag[1], acc1, 0, 0, 0);
        acc2 = __builtin_amdgcn_mfma_f32_16x16x32_bf16(af, frag[2], acc2, 0, 0, 0);
        acc3 = __builtin_amdgcn_mfma_f32_16x16x32_bf16(af, frag[3], acc3, 0, 0, 0);
    }

    // C/D layout (16x16x32): col = lane&15, row = quad*4 + reg
    float* pp = part + (size_t)(b * gridDim.x + chunk) * 4096;
#pragma unroll
    for (int rr = 0; rr < 4; ++rr) {
        const int m = w * 16 + q * 4 + rr;
        pp[m * 64 + (0 * 16 + r)] = acc0[rr];
        pp[m * 64 + (1 * 16 + r)] = acc1[rr];
        pp[m * 64 + (2 * 16 + r)] = acc2[rr];
        pp[m * 64 + (3 * 16 + r)] = acc3[rr];
    }
}

// ---------------------------------------------------------------------------
// K2a: reduce partial Grams -> G[b][64*64]
// ---------------------------------------------------------------------------
__global__ __launch_bounds__(256) void k_reduce(const float* __restrict__ part,
                                                float* __restrict__ G,
                                                int chunks) {
    const int b    = blockIdx.y;
    const int cell = blockIdx.x * 512 + threadIdx.x;
    float s0 = 0.f, s1 = 0.f;
    for (int p = 0; p < chunks; ++p) {
        const float* pp = part + (size_t)(b * chunks + p) * 4096;
        s0 += pp[cell];
        s1 += pp[cell + 256];
    }
    G[b * 4096 + cell]       = s0;
    G[b * 4096 + cell + 256] = s1;
}

// ---------------------------------------------------------------------------
// K2b: S = bf16( gamma * sigmoid(G@G) )   (G symmetric -> row-row dots)
// gamma is folded into S so K3's bf16 matmul error is scaled by 1e-4;
// the "+x" residual is applied exactly in fp32 inside K3.
// ---------------------------------------------------------------------------
__global__ __launch_bounds__(256) void k_affinity(const float* __restrict__ G,
                                                  const float* __restrict__ gptr,
                                                  __bf16* __restrict__ S) {
    const int b = blockIdx.x;
    __shared__ float Gs[64 * 65];                 // +1 pad: break 64-stride conflicts
    const float* Gb = G + b * 4096;
    for (int i = threadIdx.x; i < 4096; i += 256)
        Gs[(i >> 6) * 65 + (i & 63)] = Gb[i];
    __syncthreads();
    const float gamma = gptr[0];
    for (int id = threadIdx.x; id < 4096; id += 256) {
        const int c = id >> 6, e = id & 63;
        float dot = 0.f;
#pragma unroll
        for (int d = 0; d < 64; ++d)
            dot += Gs[c * 65 + d] * Gs[e * 65 + d];
        const float aff = 1.0f / (1.0f + __expf(-dot));
        S[b * 4096 + id] = (__bf16)(gamma * aff);
    }
}

// ---------------------------------------------------------------------------
// K3: out = x + S @ K via bf16 MFMA (HBM-bound: 226 MB read + 226 MB write).
// Block = 256 threads = 4 waves, 256 columns of n per block.
// Wave w handles 16-column strips n0 = blk*256 + w*16 + it*64, it=0..3
// (waves cover contiguous 256 B -> full L2 lines consumed concurrently).
// A-frags (S rows, bf16) loaded once per thread; B-frags (K columns) loaded
// as 8 strided fp32 dwords/lane (4x64B segments per instr) and converted.
// D layout: col = lane&15 (n), row = quad*4+reg (c). Residual x added fp32.
// ---------------------------------------------------------------------------
__global__ __launch_bounds__(256) void k_apply(const float* __restrict__ x,
                                               const __bf16* __restrict__ S,
                                               float* __restrict__ out) {
    const int b    = blockIdx.y;
    const int tid  = threadIdx.x;
    const int w    = tid >> 6;
    const int lane = tid & 63;
    const int r    = lane & 15;
    const int q    = lane >> 4;

    const float*  xb = x + (size_t)b * CN;
    float*        ob = out + (size_t)b * CN;
    const __bf16* Sb = S + b * 4096;

    // A-frags: a[ct][kh] holds S[ct*16 + r][kh*32 + q*8 .. +7]  (16B loads)
    bf16x8 a[4][2];
#pragma unroll
    for (int ct = 0; ct < 4; ++ct)
#pragma unroll
        for (int kh = 0; kh < 2; ++kh)
            a[ct][kh] = *(const bf16x8*)(Sb + (ct * 16 + r) * 64 + kh * 32 + q * 8);

    const int nbase = blockIdx.x * 256 + w * 16 + r;

#pragma unroll 2
    for (int it = 0; it < 4; ++it) {
        const int n = nbase + it * 64;

        // B-frags: bfr[kh] holds K[kh*32 + q*8 + j][n], j=0..7
        bf16x8 bfr[2];
#pragma unroll
        for (int kh = 0; kh < 2; ++kh) {
            const float* p = xb + (size_t)(kh * 32 + q * 8) * NCOL + n;
            bf16x8 f;
#pragma unroll
            for (int j = 0; j < 8; ++j)
                f[j] = (__bf16)p[(size_t)j * NCOL];
            bfr[kh] = f;
        }

        f32x4 acc[4];
#pragma unroll
        for (int ct = 0; ct < 4; ++ct) {
            f32x4 z = {0.f, 0.f, 0.f, 0.f};
            z = __builtin_amdgcn_mfma_f32_16x16x32_bf16(a[ct][0], bfr[0], z, 0, 0, 0);
            z = __builtin_amdgcn_mfma_f32_16x16x32_bf16(a[ct][1], bfr[1], z, 0, 0, 0);
            acc[ct] = z;
        }

        // residual + store: row c = ct*16 + q*4 + rr, col n (exact fp32 x)
#pragma unroll
        for (int ct = 0; ct < 4; ++ct) {
#pragma unroll
            for (int rr = 0; rr < 4; ++rr) {
                const size_t o = (size_t)(ct * 16 + q * 4 + rr) * NCOL + n;
                ob[o] = xb[o] + acc[ct][rr];
            }
        }
    }
}

// ---------------------------------------------------------------------------
extern "C" void kernel_launch(void* const* d_in, const int* in_sizes, int n_in,
                              void* d_out, int out_size, void* d_ws, size_t ws_size,
                              hipStream_t stream) {
    const float* x    = (const float*)d_in[0];
    const float* gptr = (const float*)d_in[1];
    float*       out  = (float*)d_out;
    float*       ws   = (float*)d_ws;

    // 3456 k32-steps per batch must split evenly across chunks.
    int chunks = 128;
    auto need = [](int ch) { return (size_t)(8 * ch + 8) * 4096 * 4 + 8 * 4096 * 2; };
    if (ws_size < need(128)) chunks = 64;
    if (ws_size < need(64))  chunks = 32;
    if (ws_size < need(32))  chunks = 8;
    if (ws_size < need(8))   chunks = 2;
    const int steps = 3456 / chunks;

    float*  part = ws;
    float*  G    = ws + (size_t)8 * chunks * 4096;
    __bf16* S    = (__bf16*)(G + 8 * 4096);

    k_gram    <<<dim3(chunks, 8), 256, 0, stream>>>(x, part, steps);
    k_reduce  <<<dim3(8, 8),      256, 0, stream>>>(part, G, chunks);
    k_affinity<<<8,               256, 0, stream>>>(G, gptr, S);
    k_apply   <<<dim3(432, 8),    256, 0, stream>>>(x, S, out);
}